// Round 10
// baseline (217.987 us; speedup 1.0000x reference)
//
#include <hip/hip_runtime.h>
#include <hip/hip_bf16.h>
#include <stdint.h>

#define BB 4
#define NN 512
#define HH 8

typedef __attribute__((ext_vector_type(4))) float f32x4;
typedef __attribute__((ext_vector_type(8))) __bf16 bf16x8;
typedef unsigned short u16;

__device__ __forceinline__ u16 f2bf(float f) {
    uint32_t u = __float_as_uint(f);
    u += 0x7FFFu + ((u >> 16) & 1u);   // round-to-nearest-even
    return (u16)(u >> 16);
}

// ---------------- diagnostic: fills fp32 output with a marker ----------------
__global__ __launch_bounds__(256) void marker_k(float* __restrict__ out,
                                                float val, int n) {
    int i = blockIdx.x * 256 + threadIdx.x;
    if (i < n) out[i] = val;
}

// ---------------- P0: We^T -> bf16, and sg[b,d] = g@Wg + bg + be + b2 ----------------
__global__ __launch_bounds__(256) void prep0(
    const float* __restrict__ We, const float* __restrict__ graph,
    const float* __restrict__ Wg, const float* __restrict__ bg,
    const float* __restrict__ be, const float* __restrict__ b2,
    u16* __restrict__ weT, float* __restrict__ sg) {
    int blk = blockIdx.x, tid = threadIdx.x;
    if (blk == 0) {
        for (int idx = tid; idx < 128 * 128; idx += 256) {
            int n = idx >> 7, k = idx & 127;
            weT[idx] = f2bf(We[k * 128 + n]);   // weT[n][k] = We[k][n]
        }
    } else {
        int b = blk - 1;
        if (tid < 128) {
            float acc = bg[tid] + be[tid] + b2[tid];
            for (int k = 0; k < 128; ++k)
                acc += graph[b * 128 + k] * Wg[k * 128 + tid];
            sg[b * 128 + tid] = acc;
        }
    }
}

// ---------------- P1: s1 = zW1+b1, s2c = zW2+sg, values, skip ----------------
__global__ __launch_bounds__(256) void prep1(
    const float* __restrict__ node, const float* __restrict__ hidden,
    const float* __restrict__ Wm, const float* __restrict__ bm,
    const float* __restrict__ Ws, const float* __restrict__ bs,
    const float* __restrict__ W1, const float* __restrict__ b1,
    const float* __restrict__ W2, const float* __restrict__ sg,
    float* __restrict__ s1, float* __restrict__ s2c,
    float* __restrict__ sv, float* __restrict__ ss) {
    __shared__ float zsh[8 * 256];
    int blk = blockIdx.x;            // 256 blocks: 64 per batch, 8 rows each
    int b = blk >> 6;
    int n0 = (blk & 63) << 3;
    int tid = threadIdx.x;
    for (int idx = tid; idx < 8 * 256; idx += 256) {
        int row = idx >> 8, k = idx & 255;
        size_t g = (size_t)(b * NN + n0 + row) * 128;
        zsh[idx] = (k < 128) ? node[g + k] : hidden[g + k - 128];
    }
    __syncthreads();
    int half = tid >> 7;             // 0/1 -> rows 0-3 / 4-7
    int t = tid & 127;               // output dim
    int r0 = half * 4;
    float am[4] = {0,0,0,0}, a1[4] = {0,0,0,0}, a2[4] = {0,0,0,0}, as_[4] = {0,0,0,0};
    for (int k = 0; k < 256; ++k) {
        float wm = Wm[k * 128 + t], w1 = W1[k * 128 + t];
        float w2 = W2[k * 128 + t], ws = Ws[k * 128 + t];
        #pragma unroll
        for (int r = 0; r < 4; ++r) {
            float z = zsh[(r0 + r) * 256 + k];
            am[r] += z * wm; a1[r] += z * w1; a2[r] += z * w2; as_[r] += z * ws;
        }
    }
    float sgv = sg[b * 128 + t];
    #pragma unroll
    for (int r = 0; r < 4; ++r) {
        int n = n0 + r0 + r;
        size_t rowoff = (size_t)(b * NN + n) * 128 + t;
        s1[rowoff]  = a1[r] + b1[t];
        s2c[rowoff] = a2[r] + sgv;
        ss[rowoff]  = as_[r] + bs[t];
        sv[(size_t)((b * HH + (t >> 4)) * NN + n) * 16 + (t & 15)] = am[r] + bm[t];
    }
}

// ---------------- Fused v6: age-ordered 2-deep pipeline (counted vmcnt by construction) ----
// block = (b,i); 4 waves; wave owns n-cols [wid*32,+32) = heads 2wid,2wid+1.
// Issue order per phase s: s1[s+1], e[s+2], cvt(e[s]) -> every wait targets
// loads >=1 phase old; e[s+1] NEVER drained early. 3 e-bufs, 2 s1-bufs, 16
// unrolled phases, raw s_barrier + lgkmcnt(0) only.
__global__ __launch_bounds__(256, 3) void fused_att6(
    const float* __restrict__ edge, const u16* __restrict__ weT,
    const float* __restrict__ s1, const float* __restrict__ s2c,
    const float* __restrict__ adj, const float* __restrict__ Aw,
    const float* __restrict__ Ab, const float* __restrict__ sv,
    const float* __restrict__ ss, float* __restrict__ out) {
    // region0: gemm-phase = bufA(8K)+bufB(8K) bf16 strips; PV-phase = scratch
    __shared__ __align__(16) char region0[20480];
    __shared__ float logit_lds[HH][NN];                  // 16 KB
    __shared__ float mask_lds[NN];                       // 2 KB
    char* bufA = region0;
    char* bufB = region0 + 8192;

    const int bid = (blockIdx.x & 7) * 256 + (blockIdx.x >> 3);  // XCD-chunked
    const int i = bid & (NN - 1);
    const int b = bid >> 9;
    const int tid = threadIdx.x;
    const int lane = tid & 63, wid = tid >> 6;
    const int l15 = lane & 15, l4 = lane >> 4;

    const float* ebase = edge + (size_t)(b * NN + i) * NN * 128;
    const float* s1b = s1 + (size_t)b * NN * 128;

    // wave's quarter of a strip: rows [wid*8, +8), 1024 floats, coalesced 1KB/instr
    #define LOADE(e, s) do {                                                \
        const float* sb = ebase + (size_t)(s) * 4096 + wid * 1024;          \
        _Pragma("unroll")                                                   \
        for (int q = 0; q < 4; ++q)                                         \
            e[q] = *(const float4*)(sb + q * 256 + lane * 4);               \
    } while (0)

    // convert 16 floats -> bf16, write 4x8B XOR-swizzled (byte ^= (row&7)<<4)
    #define CVT_WRITE(e, buf) do {                                          \
        _Pragma("unroll")                                                   \
        for (int q = 0; q < 4; ++q) {                                       \
            const int row = (wid << 3) + (q << 1) + (lane >> 5);            \
            const int byt = row * 256 + ((((lane & 31) << 3) ^ ((row & 7) << 4))); \
            union { uint2 u; __bf16 h[4]; } t;                              \
            t.h[0] = (__bf16)e[q].x; t.h[1] = (__bf16)e[q].y;               \
            t.h[2] = (__bf16)e[q].z; t.h[3] = (__bf16)e[q].w;               \
            *(uint2*)(buf + byt) = t.u;                                     \
        }                                                                   \
    } while (0)

    #define LOADS1(sv1, s) do {                                             \
        _Pragma("unroll")                                                   \
        for (int jf = 0; jf < 2; ++jf)                                      \
            _Pragma("unroll")                                               \
            for (int nf = 0; nf < 2; ++nf)                                  \
                sv1[jf][nf] = *(const float4*)(                             \
                    s1b + (size_t)((s) * 32 + jf * 16 + l15) * 128          \
                        + wid * 32 + nf * 16 + l4 * 4);                     \
    } while (0)

    // compute strip s from bf16 buf; epilogue -> logit_lds
    #define COMPUTE(buf, sv1, s) do {                                       \
        f32x4 acc[2][2];                                                    \
        _Pragma("unroll")                                                   \
        for (int nf = 0; nf < 2; ++nf) {                                    \
            const f32x4 ini = {s2v4[nf].x, s2v4[nf].y, s2v4[nf].z, s2v4[nf].w}; \
            acc[nf][0] = ini; acc[nf][1] = ini;                             \
        }                                                                   \
        _Pragma("unroll")                                                   \
        for (int kk = 0; kk < 4; ++kk) {                                    \
            const int ko = (kk * 64 + l4 * 16);                             \
            const bf16x8 b0 = *(const bf16x8*)(buf + (0 * 16 + l15) * 256 + (ko ^ ((l15 & 7) << 4))); \
            const bf16x8 b1 = *(const bf16x8*)(buf + (1 * 16 + l15) * 256 + (ko ^ ((l15 & 7) << 4))); \
            acc[0][0] = __builtin_amdgcn_mfma_f32_16x16x32_bf16(afw[0][kk], b0, acc[0][0], 0, 0, 0); \
            acc[1][0] = __builtin_amdgcn_mfma_f32_16x16x32_bf16(afw[1][kk], b0, acc[1][0], 0, 0, 0); \
            acc[0][1] = __builtin_amdgcn_mfma_f32_16x16x32_bf16(afw[0][kk], b1, acc[0][1], 0, 0, 0); \
            acc[1][1] = __builtin_amdgcn_mfma_f32_16x16x32_bf16(afw[1][kk], b1, acc[1][1], 0, 0, 0); \
        }                                                                   \
        _Pragma("unroll")                                                   \
        for (int jf = 0; jf < 2; ++jf) {                                    \
            _Pragma("unroll")                                               \
            for (int nf = 0; nf < 2; ++nf) {                                \
                const float s1r[4] = {sv1[jf][nf].x, sv1[jf][nf].y,         \
                                      sv1[jf][nf].z, sv1[jf][nf].w};        \
                const float awr[4] = {aw4[nf].x, aw4[nf].y, aw4[nf].z, aw4[nf].w}; \
                float t = 0.0f;                                             \
                _Pragma("unroll")                                           \
                for (int r = 0; r < 4; ++r) {                               \
                    float p = acc[nf][jf][r] + s1r[r];                      \
                    p = fmaxf(p, 0.01f * p);                                \
                    t += p * awr[r];                                        \
                }                                                           \
                t += __shfl_xor(t, 16);                                     \
                t += __shfl_xor(t, 32);                                     \
                if (lane < 16)                                              \
                    logit_lds[wid * 2 + nf][(s) * 32 + jf * 16 + l15] = t + abv[nf]; \
            }                                                               \
        }                                                                   \
    } while (0)

    #define BARRIER_NOVM() do {                                             \
        __builtin_amdgcn_sched_barrier(0);                                  \
        asm volatile("s_waitcnt lgkmcnt(0)" ::: "memory");                  \
        __builtin_amdgcn_s_barrier();                                       \
        __builtin_amdgcn_sched_barrier(0);                                  \
    } while (0)

    // phase s: issue s1[s+1] (before e!), then e[s+2]; cvt e[s]; barrier; compute s.
    // Age order guarantees: wait(e[s]) leaves e[s+1],e[s+2] in flight;
    // wait(s1[s]) (inside COMPUTE) leaves e[s+1],s1[s+1],e[s+2] in flight.
    #define PHASE(eCur, eN2, s1Cur, s1Nxt, s) do {                          \
        if ((s) + 1 < 16) LOADS1(s1Nxt, (s) + 1);                           \
        if ((s) + 2 < 16) LOADE(eN2, (s) + 2);                              \
        CVT_WRITE(eCur, (((s) & 1) ? bufB : bufA));                         \
        BARRIER_NOVM();                                                     \
        COMPUTE((((s) & 1) ? bufB : bufA), s1Cur, s);                       \
    } while (0)

    float4 eA[4], eB[4], eC[4];
    float4 s1vA[2][2], s1vB[2][2];

    LOADS1(s1vA, 0);
    LOADE(eA, 0);
    LOADE(eB, 1);

    // A-fragments: weT rows n = wid*32+nf*16+l15 (L2-resident)
    bf16x8 afw[2][4];
    #pragma unroll
    for (int nf = 0; nf < 2; ++nf) {
        const int bn = wid * 32 + nf * 16 + l15;
        #pragma unroll
        for (int kk = 0; kk < 4; ++kk)
            afw[nf][kk] = *(const bf16x8*)(weT + bn * 128 + kk * 32 + l4 * 8);
    }

    const float* arow = adj + (size_t)(b * NN + i) * NN;
    for (int j = tid; j < NN; j += 256) mask_lds[j] = (arow[j] - 1.0f) * 1e9f;

    float4 s2v4[2], aw4[2];
    float abv[2];
    #pragma unroll
    for (int nf = 0; nf < 2; ++nf) {
        const int n0 = wid * 32 + nf * 16 + l4 * 4;
        s2v4[nf] = *(const float4*)(s2c + (size_t)(b * NN + i) * 128 + n0);
        aw4[nf]  = *(const float4*)(Aw + n0);
        abv[nf]  = Ab[wid * 2 + nf];
    }
    __syncthreads();   // one-time full barrier: mask_lds visible

    PHASE(eA, eC, s1vA, s1vB, 0);
    PHASE(eB, eA, s1vB, s1vA, 1);
    PHASE(eC, eB, s1vA, s1vB, 2);
    PHASE(eA, eC, s1vB, s1vA, 3);
    PHASE(eB, eA, s1vA, s1vB, 4);
    PHASE(eC, eB, s1vB, s1vA, 5);
    PHASE(eA, eC, s1vA, s1vB, 6);
    PHASE(eB, eA, s1vB, s1vA, 7);
    PHASE(eC, eB, s1vA, s1vB, 8);
    PHASE(eA, eC, s1vB, s1vA, 9);
    PHASE(eB, eA, s1vA, s1vB, 10);
    PHASE(eC, eB, s1vB, s1vA, 11);
    PHASE(eA, eC, s1vA, s1vB, 12);
    PHASE(eB, eA, s1vB, s1vA, 13);
    PHASE(eC, eB, s1vA, s1vB, 14);
    PHASE(eA, eC, s1vB, s1vA, 15);

    __syncthreads();   // logits visible to all

    // masked softmax: wave wid handles heads 2wid, 2wid+1
    #pragma unroll
    for (int hh = 0; hh < 2; ++hh) {
        const int h = wid * 2 + hh;
        float lv[8];
        float m = -3.0e38f;
        #pragma unroll
        for (int q = 0; q < 8; ++q) {
            float l = logit_lds[h][lane + q * 64] + mask_lds[lane + q * 64];
            lv[q] = l;
            m = fmaxf(m, l);
        }
        #pragma unroll
        for (int off = 32; off; off >>= 1) m = fmaxf(m, __shfl_xor(m, off));
        float s = 0.0f;
        #pragma unroll
        for (int q = 0; q < 8; ++q) { lv[q] = __expf(lv[q] - m); s += lv[q]; }
        #pragma unroll
        for (int off = 32; off; off >>= 1) s += __shfl_xor(s, off);
        const float inv = 1.0f / s;
        #pragma unroll
        for (int q = 0; q < 8; ++q)
            logit_lds[h][lane + q * 64] = lv[q] * inv;
    }
    __syncthreads();

    // PV: wave wid -> heads 2wid,2wid+1; lane owns j = q*64+lane; coalesced sv reads
    float* scr = (float*)region0 + wid * 1280;   // 64 lanes x 20 floats
    const float* ssb = ss + (size_t)(b * NN + i) * 128;
    float outv[2];
    #pragma unroll
    for (int hh = 0; hh < 2; ++hh) {
        const int h = wid * 2 + hh;
        const float* svh = sv + (size_t)(b * HH + h) * NN * 16;
        f32x4 a0 = {0,0,0,0}, a1 = {0,0,0,0}, a2 = {0,0,0,0}, a3 = {0,0,0,0};
        #pragma unroll
        for (int q = 0; q < 8; ++q) {
            const int j = q * 64 + lane;
            const float c = logit_lds[h][j];
            const float4* vj = (const float4*)(svh + (size_t)j * 16);
            const float4 v0 = vj[0], v1 = vj[1], v2 = vj[2], v3 = vj[3];
            a0[0] += c * v0.x; a0[1] += c * v0.y; a0[2] += c * v0.z; a0[3] += c * v0.w;
            a1[0] += c * v1.x; a1[1] += c * v1.y; a1[2] += c * v1.z; a1[3] += c * v1.w;
            a2[0] += c * v2.x; a2[1] += c * v2.y; a2[2] += c * v2.z; a2[3] += c * v2.w;
            a3[0] += c * v3.x; a3[1] += c * v3.y; a3[2] += c * v3.z; a3[3] += c * v3.w;
        }
        *(f32x4*)(scr + lane * 20 + 0)  = a0;
        *(f32x4*)(scr + lane * 20 + 4)  = a1;
        *(f32x4*)(scr + lane * 20 + 8)  = a2;
        *(f32x4*)(scr + lane * 20 + 12) = a3;
        float p = 0.0f;
        #pragma unroll
        for (int t = 0; t < 16; ++t)
            p += scr[(l4 * 16 + t) * 20 + l15];
        p += __shfl_xor(p, 16);
        p += __shfl_xor(p, 32);
        outv[hh] = p;     // lanes 0-15 hold sum for d = l15
    }
    if (lane < 16) {
        const size_t o = (size_t)(b * NN + i) * 128 + (wid * 2) * 16 + lane;
        out[o]      = fmaxf(outv[0] + ssb[(wid * 2) * 16 + lane], 0.0f);
        out[o + 16] = fmaxf(outv[1] + ssb[(wid * 2) * 16 + lane + 16], 0.0f);
    }
    #undef LOADE
    #undef CVT_WRITE
    #undef LOADS1
    #undef COMPUTE
    #undef BARRIER_NOVM
    #undef PHASE
}

extern "C" void kernel_launch(void* const* d_in, const int* in_sizes, int n_in,
                              void* d_out, int out_size, void* d_ws, size_t ws_size,
                              hipStream_t stream) {
    const float* node   = (const float*)d_in[0];
    const float* edge   = (const float*)d_in[1];
    const float* graph  = (const float*)d_in[2];
    const float* adj    = (const float*)d_in[3];
    const float* hidden = (const float*)d_in[4];
    const float* Wm = (const float*)d_in[5];
    const float* bm = (const float*)d_in[6];
    const float* Ws = (const float*)d_in[7];
    const float* bs = (const float*)d_in[8];
    const float* W1 = (const float*)d_in[9];
    const float* b1 = (const float*)d_in[10];
    const float* W2 = (const float*)d_in[11];
    const float* b2 = (const float*)d_in[12];
    const float* We = (const float*)d_in[13];
    const float* be = (const float*)d_in[14];
    const float* Wg = (const float*)d_in[15];
    const float* bg = (const float*)d_in[16];
    const float* Aw = (const float*)d_in[17];
    const float* Ab = (const float*)d_in[18];

    float* outp = (float*)d_out;   // reference output dtype is float32
    const size_t WS_NEEDED = 34816 + 4u * 1048576u;   // ~4.03 MiB

    if (ws_size < WS_NEEDED) {
        marker_k<<<(out_size + 255) / 256, 256, 0, stream>>>(
            outp, 2000.0f + (float)(ws_size >> 20), out_size);
        return;
    }

    char* ws = (char*)d_ws;
    u16*   weT = (u16*)ws;                                // 32768 B
    float* sg  = (float*)(ws + 32768);                    // 2048 B
    float* s1  = (float*)(ws + 34816);                    // 1 MiB
    float* s2c = (float*)(ws + 34816 + 1048576);          // 1 MiB
    float* sv  = (float*)(ws + 34816 + 2 * 1048576);      // 1 MiB
    float* ss  = (float*)(ws + 34816 + 3 * 1048576);      // 1 MiB

    prep0<<<1 + BB, 256, 0, stream>>>(We, graph, Wg, bg, be, b2, weT, sg);
    prep1<<<256, 256, 0, stream>>>(node, hidden, Wm, bm, Ws, bs, W1, b1, W2,
                                   sg, s1, s2c, sv, ss);
    fused_att6<<<BB * NN, 256, 0, stream>>>(edge, weT, s1, s2c, adj, Aw, Ab,
                                            sv, ss, outp);
}